// Round 1
// baseline (553.120 us; speedup 1.0000x reference)
//
#include <hip/hip_runtime.h>
#include <hip/hip_bf16.h>

#define NHEADS 16
#define HDIM   64
#define HID    1024
#define BB     4
#define SS     4096
#define MM     (BB*SS)      // 16384 rows
#define KK     HID          // 1024
#define NN     (2*HID)      // 2048 cols (Q | K)

using short8 = __attribute__((ext_vector_type(8))) short;
using f32x4  = __attribute__((ext_vector_type(4))) float;

__device__ __forceinline__ float bf2f(ushort u) {
  return __uint_as_float(((unsigned)u) << 16);
}
__device__ __forceinline__ ushort f2bf(float f) {
  unsigned u = __float_as_uint(f);
  unsigned r = (u + 0x7fffu + ((u >> 16) & 1u)) >> 16;  // RNE
  return (ushort)r;
}

// ---------------------------------------------------------------- cast hs->bf16
__global__ __launch_bounds__(256) void cast_hs_k(const float* __restrict__ in,
                                                 ushort* __restrict__ out) {
  size_t i = ((size_t)blockIdx.x * 256 + threadIdx.x) * 8;
  float4 a = *(const float4*)(in + i);
  float4 b = *(const float4*)(in + i + 4);
  ushort r[8];
  r[0]=f2bf(a.x); r[1]=f2bf(a.y); r[2]=f2bf(a.z); r[3]=f2bf(a.w);
  r[4]=f2bf(b.x); r[5]=f2bf(b.y); r[6]=f2bf(b.z); r[7]=f2bf(b.w);
  *(uint4*)(out + i) = *(const uint4*)r;
}

// ------------------------------------------- W (K,N) -> Bt (N,K) bf16, Wq|Wkv fused
__global__ __launch_bounds__(256) void wcast_k(const float* __restrict__ Wq,
                                               const float* __restrict__ Wkv,
                                               ushort* __restrict__ Bt) {
  __shared__ float tile[32][33];
  int k0 = blockIdx.x * 32, n0 = blockIdx.y * 32;
  int tx = threadIdx.x, ty = threadIdx.y;
  const float* src = (n0 < HID) ? Wq : Wkv;
  int nc = (n0 < HID) ? n0 : n0 - HID;
#pragma unroll
  for (int j = 0; j < 4; ++j)
    tile[ty + 8*j][tx] = src[(size_t)(k0 + ty + 8*j) * HID + nc + tx];
  __syncthreads();
#pragma unroll
  for (int j = 0; j < 4; ++j)
    Bt[(size_t)(n0 + ty + 8*j) * KK + k0 + tx] = f2bf(tile[tx][ty + 8*j]);
}

// ---------------------------------------------------------------- fused QK GEMM
// C[M][N] = A[M][K] @ B, B given transposed as Bt[N][K]; bias added per column.
// 128x128 tile, BK=64, 4 waves (2x2), 16x16x32 bf16 MFMA.
__global__ __launch_bounds__(256) void gemm_k(const ushort* __restrict__ A,
                                              const ushort* __restrict__ Bt,
                                              const float* __restrict__ bq,
                                              const float* __restrict__ bkv,
                                              ushort* __restrict__ C) {
  __shared__ __align__(16) ushort As[128 * 72];  // padded stride 72 elems
  __shared__ __align__(16) ushort Bs[128 * 72];
  const int tid = threadIdx.x;
  const int tn = blockIdx.x, tm = blockIdx.y;
  const int w = tid >> 6, lane = tid & 63;
  const int wr = w >> 1, wc = w & 1;
  const int lr = lane & 15;          // frag row/col within 16
  const int lk = (lane >> 4) * 8;    // frag k offset within 32

  const ushort* Ab = A  + (size_t)tm * 128 * KK;
  const ushort* Bb = Bt + (size_t)tn * 128 * KK;

  int r[4], c8[4];
#pragma unroll
  for (int i = 0; i < 4; ++i) { int ch = tid + 256*i; r[i] = ch >> 3; c8[i] = ch & 7; }

  uint4 ra[4], rb[4];
#pragma unroll
  for (int i = 0; i < 4; ++i) {
    ra[i] = *(const uint4*)(Ab + (size_t)r[i]*KK + c8[i]*8);
    rb[i] = *(const uint4*)(Bb + (size_t)r[i]*KK + c8[i]*8);
  }

  f32x4 acc[4][4];
#pragma unroll
  for (int m = 0; m < 4; ++m)
#pragma unroll
    for (int n = 0; n < 4; ++n) acc[m][n] = (f32x4){0.f,0.f,0.f,0.f};

  for (int kt = 0; kt < KK/64; ++kt) {
    __syncthreads();
#pragma unroll
    for (int i = 0; i < 4; ++i) {
      *(uint4*)(As + r[i]*72 + c8[i]*8) = ra[i];
      *(uint4*)(Bs + r[i]*72 + c8[i]*8) = rb[i];
    }
    __syncthreads();
    if (kt + 1 < KK/64) {
      int ko = (kt + 1) * 64;
#pragma unroll
      for (int i = 0; i < 4; ++i) {
        ra[i] = *(const uint4*)(Ab + (size_t)r[i]*KK + ko + c8[i]*8);
        rb[i] = *(const uint4*)(Bb + (size_t)r[i]*KK + ko + c8[i]*8);
      }
    }
#pragma unroll
    for (int kk = 0; kk < 64; kk += 32) {
      short8 af[4], bfv[4];
#pragma unroll
      for (int m = 0; m < 4; ++m)
        af[m] = *(const short8*)(As + (wr*64 + m*16 + lr)*72 + kk + lk);
#pragma unroll
      for (int n = 0; n < 4; ++n)
        bfv[n] = *(const short8*)(Bs + (wc*64 + n*16 + lr)*72 + kk + lk);
#pragma unroll
      for (int m = 0; m < 4; ++m)
#pragma unroll
        for (int n = 0; n < 4; ++n)
          acc[m][n] = __builtin_amdgcn_mfma_f32_16x16x32_bf16(af[m], bfv[n], acc[m][n], 0, 0, 0);
    }
  }

  const int rr = (lane >> 4) * 4;
#pragma unroll
  for (int n = 0; n < 4; ++n) {
    int col = tn*128 + wc*64 + n*16 + lr;
    float bias = (col < HID) ? bq[col] : bkv[col - HID];
#pragma unroll
    for (int m = 0; m < 4; ++m) {
      int row0 = tm*128 + wr*64 + m*16 + rr;
#pragma unroll
      for (int t = 0; t < 4; ++t)
        C[(size_t)(row0 + t)*NN + col] = f2bf(acc[m][n][t] + bias);
    }
  }
}

// ------------------------------------------------- global attention (1 q vs S keys)
// one block per (b,h); 16 waves; scores in LDS; writes gvec + context row s=0
__global__ __launch_bounds__(1024) void global_attn_k(const ushort* __restrict__ QK,
                                                      const float* __restrict__ mask,
                                                      float* __restrict__ ctx,
                                                      float* __restrict__ gvec) {
  const int b = blockIdx.x >> 4, h = blockIdx.x & 15;
  const int tid = threadIdx.x, w = tid >> 6, lane = tid & 63;
  __shared__ float sc[SS];
  __shared__ float red[16];
  __shared__ float gacc[16][64];

  const float gq = bf2f(QK[(size_t)b*SS*NN + h*HDIM + lane]);  // Q row s=0
  float mx = -1e30f;
  for (int s = w; s < SS; s += 16) {
    float kv = bf2f(QK[((size_t)b*SS + s)*NN + HID + h*HDIM + lane]);
    float p = gq * kv;
#pragma unroll
    for (int o = 32; o; o >>= 1) p += __shfl_xor(p, o, 64);
    p = p * 0.125f + mask[b*SS + s];
    if (lane == 0) sc[s] = p;
    mx = fmaxf(mx, p);
  }
  if (lane == 0) red[w] = mx;
  __syncthreads();
  float bm = -1e30f;
#pragma unroll
  for (int i = 0; i < 16; ++i) bm = fmaxf(bm, red[i]);
  float ls = 0.f;
  for (int s = tid; s < SS; s += 1024) {
    float e = __expf(sc[s] - bm);
    sc[s] = e;
    ls += e;
  }
#pragma unroll
  for (int o = 32; o; o >>= 1) ls += __shfl_xor(ls, o, 64);
  __syncthreads();
  if (lane == 0) red[w] = ls;
  __syncthreads();
  float tot = 0.f;
#pragma unroll
  for (int i = 0; i < 16; ++i) tot += red[i];
  const float inv = 1.f / tot;

  float acc = 0.f;
  for (int s = w; s < SS; s += 16)
    acc += sc[s] * bf2f(QK[((size_t)b*SS + s)*NN + HID + h*HDIM + lane]);
  gacc[w][lane] = acc;
  __syncthreads();
  if (w == 0) {
    float g = 0.f;
#pragma unroll
    for (int i = 0; i < 16; ++i) g += gacc[i][lane];
    g *= inv;
    gvec[b*HID + h*HDIM + lane] = g;
    ctx[(size_t)b*SS*HID + h*HDIM + lane] = g;
  }
}

// ------------------------------------------------- local attention (4 keys/pos)
__device__ __forceinline__ void unpack16(const ushort* __restrict__ p, float* f) {
  uint4 v0 = *(const uint4*)p;
  uint4 v1 = *(const uint4*)(p + 8);
  unsigned u[8] = {v0.x, v0.y, v0.z, v0.w, v1.x, v1.y, v1.z, v1.w};
#pragma unroll
  for (int i = 0; i < 8; ++i) {
    f[2*i]   = __uint_as_float(u[i] << 16);
    f[2*i+1] = __uint_as_float(u[i] & 0xffff0000u);
  }
}

__global__ __launch_bounds__(256) void local_attn_k(const ushort* __restrict__ QK,
                                                    const float* __restrict__ gvec,
                                                    float* __restrict__ out) {
  const int blk = blockIdx.x;
  const int b = blk >> 10;
  const int s = 1 + ((blk & 1023) << 2) + (int)(threadIdx.x >> 6);
  if (s >= SS) return;
  const int lane = threadIdx.x & 63;
  const int g = lane >> 2, j = lane & 3;
  const int db = g*HDIM + j*16;

  const size_t base = ((size_t)b*SS + s) * NN;
  const ushort* qp  = QK + base + db;
  const ushort* ksp = QK + base + HID + db;
  const ushort* kpp = QK + base - NN + HID + db;
  const int sn = (s == SS-1) ? 0 : s + 1;
  const ushort* knp = QK + ((size_t)b*SS + sn)*NN + HID + db;
  const float*  gvp = gvec + b*HID + db;

  float q[16], ks[16], kp[16], kn[16], gv[16];
  unpack16(qp, q); unpack16(ksp, ks); unpack16(kpp, kp); unpack16(knp, kn);
#pragma unroll
  for (int t = 0; t < 16; t += 4) *(float4*)(gv + t) = *(const float4*)(gvp + t);

  float d0=0.f, d1=0.f, d2=0.f, d3=0.f;
#pragma unroll
  for (int t = 0; t < 16; ++t) {
    d0 += q[t]*ks[t]; d1 += q[t]*gv[t]; d2 += q[t]*kp[t]; d3 += q[t]*kn[t];
  }
  d0 += __shfl_xor(d0, 1, 64); d0 += __shfl_xor(d0, 2, 64);
  d1 += __shfl_xor(d1, 1, 64); d1 += __shfl_xor(d1, 2, 64);
  d2 += __shfl_xor(d2, 1, 64); d2 += __shfl_xor(d2, 2, 64);
  d3 += __shfl_xor(d3, 1, 64); d3 += __shfl_xor(d3, 2, 64);

  float s0 = d0*0.125f, s1 = d1*0.125f, s2 = d2*0.125f, s3 = d3*0.125f;
  float m = fmaxf(fmaxf(s0, s1), fmaxf(s2, s3));
  float e0 = __expf(s0 - m), e1 = __expf(s1 - m), e2 = __expf(s2 - m), e3 = __expf(s3 - m);
  float inv = 1.f / (e0 + e1 + e2 + e3);
  float a0 = e0*inv, a1 = e1*inv, a2 = e2*inv, a3 = e3*inv;

  float o[16];
#pragma unroll
  for (int t = 0; t < 16; ++t) o[t] = a0*ks[t] + a1*gv[t] + a2*kp[t] + a3*kn[t];
  float* cp = out + ((size_t)b*SS + s)*HID + db;
#pragma unroll
  for (int t = 0; t < 16; t += 4) *(float4*)(cp + t) = *(const float4*)(o + t);

  if (j == 0) {
    float4 av; av.x = a0; av.y = a1; av.z = a2; av.w = a3;
    *(float4*)(out + (size_t)BB*SS*HID + (((size_t)b*NHEADS + g)*(SS-1) + (s-1))*4) = av;
  }
}

// ---------------------------------------------------------------------- launch
extern "C" void kernel_launch(void* const* d_in, const int* in_sizes, int n_in,
                              void* d_out, int out_size, void* d_ws, size_t ws_size,
                              hipStream_t stream) {
  const float* hs   = (const float*)d_in[0];
  const float* mask = (const float*)d_in[1];
  const float* Wq   = (const float*)d_in[2];
  const float* bq   = (const float*)d_in[3];
  const float* Wkv  = (const float*)d_in[4];
  const float* bkv  = (const float*)d_in[5];
  float* out = (float*)d_out;

  char* ws = (char*)d_ws;
  ushort* hsb  = (ushort*)ws;                                   // 32 MB
  ushort* Bt   = (ushort*)(ws + 33554432);                      // 4 MB
  ushort* QK   = (ushort*)(ws + 33554432 + 4194304);            // 64 MB
  float*  gvec = (float*)(ws + 33554432 + 4194304 + 67108864);  // 16 KB

  cast_hs_k<<<MM*KK/(256*8), 256, 0, stream>>>(hs, hsb);
  wcast_k<<<dim3(KK/32, NN/32), dim3(32, 8), 0, stream>>>(Wq, Wkv, Bt);
  gemm_k<<<dim3(NN/128, MM/128), 256, 0, stream>>>(hsb, Bt, bq, bkv, QK);
  global_attn_k<<<BB*NHEADS, 1024, 0, stream>>>(QK, mask, out, gvec);
  local_attn_k<<<BB*1024, 256, 0, stream>>>(QK, gvec, out);
}

// Round 2
// 180.710 us; speedup vs baseline: 3.0608x; 3.0608x over previous
//
#include <hip/hip_runtime.h>
#include <hip/hip_bf16.h>

#define NHEADS 16
#define HDIM   64
#define HID    1024
#define BB     4
#define SS     4096
#define MM     (BB*SS)      // 16384 rows
#define KK     HID          // 1024
#define NN     (2*HID)      // 2048 cols (Q | K)

using short8 = __attribute__((ext_vector_type(8))) short;
using f32x4  = __attribute__((ext_vector_type(4))) float;

__device__ __forceinline__ float bf2f(ushort u) {
  return __uint_as_float(((unsigned)u) << 16);
}
__device__ __forceinline__ ushort f2bf(float f) {
  unsigned u = __float_as_uint(f);
  unsigned r = (u + 0x7fffu + ((u >> 16) & 1u)) >> 16;  // RNE
  return (ushort)r;
}

__device__ __forceinline__ void gload16(const void* g, void* l) {
  __builtin_amdgcn_global_load_lds(
      (const __attribute__((address_space(1))) void*)g,
      (__attribute__((address_space(3))) void*)l, 16, 0, 0);
}

// ---------------------------------------------------------------- cast hs->bf16
__global__ __launch_bounds__(256) void cast_hs_k(const float* __restrict__ in,
                                                 ushort* __restrict__ out) {
  size_t i = ((size_t)blockIdx.x * 256 + threadIdx.x) * 8;
  float4 a = *(const float4*)(in + i);
  float4 b = *(const float4*)(in + i + 4);
  ushort r[8];
  r[0]=f2bf(a.x); r[1]=f2bf(a.y); r[2]=f2bf(a.z); r[3]=f2bf(a.w);
  r[4]=f2bf(b.x); r[5]=f2bf(b.y); r[6]=f2bf(b.z); r[7]=f2bf(b.w);
  *(uint4*)(out + i) = *(const uint4*)r;
}

// ------------------------------------------- W (K,N) -> Bt (N,K) bf16, Wq|Wkv fused
__global__ __launch_bounds__(256) void wcast_k(const float* __restrict__ Wq,
                                               const float* __restrict__ Wkv,
                                               ushort* __restrict__ Bt) {
  __shared__ float tile[32][33];
  int k0 = blockIdx.x * 32, n0 = blockIdx.y * 32;
  int tx = threadIdx.x, ty = threadIdx.y;
  const float* src = (n0 < HID) ? Wq : Wkv;
  int nc = (n0 < HID) ? n0 : n0 - HID;
#pragma unroll
  for (int j = 0; j < 4; ++j)
    tile[ty + 8*j][tx] = src[(size_t)(k0 + ty + 8*j) * HID + nc + tx];
  __syncthreads();
#pragma unroll
  for (int j = 0; j < 4; ++j)
    Bt[(size_t)(n0 + ty + 8*j) * KK + k0 + tx] = f2bf(tile[tx][ty + 8*j]);
}

// ---------------------------------------------------------------- fused QK GEMM
// C[M][N] = A[M][K] @ B, B transposed as Bt[N][K]; bias per column.
// 128x128 tile, BK=64, 4 waves (2x2), 16x16x32 bf16 MFMA.
// m97 structure: global_load_lds(16B) staging, linear LDS + XOR chunk swizzle
// (pre-swizzled global source, swizzled ds_read), LDS-staged coalesced epilogue.
__global__ __launch_bounds__(256) void gemm_k(const ushort* __restrict__ A,
                                              const ushort* __restrict__ Bt,
                                              const float* __restrict__ bq,
                                              const float* __restrict__ bkv,
                                              ushort* __restrict__ C) {
  __shared__ __align__(16) ushort lds[2 * 128 * 64];  // As | Bs ; reused for C stage
  ushort* As = lds;
  ushort* Bs = lds + 128 * 64;

  const int tid = threadIdx.x;
  const int tn = blockIdx.x, tm = blockIdx.y;
  const int w = tid >> 6, lane = tid & 63;
  const int wr = w >> 1, wc = w & 1;
  const int lr = lane & 15;
  const int hi = lane >> 4;   // 0..3

  const ushort* Ab = A  + (size_t)tm * 128 * KK;
  const ushort* Bb = Bt + (size_t)tn * 128 * KK;

  // 8 staging rounds: round i covers LDS bytes [i*4096, i*4096+4096).
  // Within a region (A: i<4, B: i>=4): row = o>>7, chunk = (o>>4)&7.
  // Source is pre-swizzled: global chunk = chunk ^ (row&7)  (rule #21).
  const ushort* gp[8];
#pragma unroll
  for (int i = 0; i < 8; ++i) {
    int o  = i * 4096 + w * 1024 + lane * 16;
    int oo = o & 16383;
    int row = oo >> 7;
    int chunk = (oo >> 4) & 7;
    gp[i] = ((i < 4) ? Ab : Bb) + (size_t)row * KK + ((chunk ^ (row & 7)) << 3);
  }

  f32x4 acc[4][4];
#pragma unroll
  for (int m = 0; m < 4; ++m)
#pragma unroll
    for (int n = 0; n < 4; ++n) acc[m][n] = (f32x4){0.f, 0.f, 0.f, 0.f};

  for (int kt = 0; kt < KK / 64; ++kt) {
    __syncthreads();
#pragma unroll
    for (int i = 0; i < 8; ++i)
      gload16(gp[i], (char*)lds + i * 4096 + w * 1024);
#pragma unroll
    for (int i = 0; i < 8; ++i) gp[i] += 64;
    __syncthreads();  // drains vmcnt -> staged data visible

#pragma unroll
    for (int kk = 0; kk < 64; kk += 32) {
      const int cbase = (kk >> 3) + hi;  // 16B-chunk index 0..7
      short8 af[4], bfv[4];
#pragma unroll
      for (int m = 0; m < 4; ++m) {
        int row = wr * 64 + m * 16 + lr;
        af[m] = *(const short8*)((const char*)As + row * 128 +
                                 ((cbase ^ (row & 7)) << 4));
      }
#pragma unroll
      for (int n = 0; n < 4; ++n) {
        int row = wc * 64 + n * 16 + lr;
        bfv[n] = *(const short8*)((const char*)Bs + row * 128 +
                                  ((cbase ^ (row & 7)) << 4));
      }
#pragma unroll
      for (int m = 0; m < 4; ++m)
#pragma unroll
        for (int n = 0; n < 4; ++n)
          acc[m][n] = __builtin_amdgcn_mfma_f32_16x16x32_bf16(af[m], bfv[n],
                                                              acc[m][n], 0, 0, 0);
    }
  }

  // ---- epilogue: stage C tile (128x128 bf16 = 32KB) in LDS, coalesced store
  __syncthreads();  // all LDS reads done before overwrite
  const int rr = hi * 4;
#pragma unroll
  for (int n = 0; n < 4; ++n) {
    int coll = wc * 64 + n * 16 + lr;
    int colg = tn * 128 + coll;
    float bias = (colg < HID) ? bq[colg] : bkv[colg - HID];
#pragma unroll
    for (int m = 0; m < 4; ++m) {
      int row0 = wr * 64 + m * 16 + rr;
#pragma unroll
      for (int t = 0; t < 4; ++t) {
        int rowt = row0 + t;
        *(ushort*)((char*)lds + rowt * 256 + ((coll * 2) ^ ((rowt & 7) << 4))) =
            f2bf(acc[m][n][t] + bias);
      }
    }
  }
  __syncthreads();
#pragma unroll
  for (int i = 0; i < 8; ++i) {
    int idx = i * 256 + tid;
    int row = idx >> 4, l16 = idx & 15;
    uint4 v = *(const uint4*)((const char*)lds + row * 256 +
                              ((l16 ^ (row & 7)) << 4));
    *(uint4*)(C + (size_t)(tm * 128 + row) * NN + tn * 128 + l16 * 8) = v;
  }
}

// ------------------------------------------------- global attention, split-K flash
// pass 1: 8 chunks of 512 keys per (b,h); partial (max, sumexp, weighted vec)
#define GCH 8
#define GCS (SS / GCH)  // 512

__global__ __launch_bounds__(512) void gattn_part_k(const ushort* __restrict__ QK,
                                                    const float* __restrict__ mask,
                                                    float* __restrict__ P) {
  const int bh = blockIdx.x >> 3, c = blockIdx.x & 7;
  const int b = bh >> 4, h = bh & 15;
  const int tid = threadIdx.x, w = tid >> 6, lane = tid & 63;
  __shared__ float sc[GCS];
  __shared__ float red[8];
  __shared__ float vacc[8][64];

  const float gq = bf2f(QK[(size_t)b * SS * NN + h * HDIM + lane]);  // Q row s=0
  const int s0 = c * GCS;
  float mx = -1e30f;
  for (int s = w; s < GCS; s += 8) {
    float kv = bf2f(QK[((size_t)b * SS + s0 + s) * NN + HID + h * HDIM + lane]);
    float p = gq * kv;
#pragma unroll
    for (int o = 32; o; o >>= 1) p += __shfl_xor(p, o, 64);
    p = p * 0.125f + mask[b * SS + s0 + s];
    if (lane == 0) sc[s] = p;
    mx = fmaxf(mx, p);
  }
  if (lane == 0) red[w] = mx;
  __syncthreads();
  float bm = -1e30f;
#pragma unroll
  for (int i = 0; i < 8; ++i) bm = fmaxf(bm, red[i]);
  __syncthreads();  // all reads of red done before overwrite
  float ls = 0.f;
  for (int s = tid; s < GCS; s += 512) {
    float e = __expf(sc[s] - bm);
    sc[s] = e;
    ls += e;
  }
#pragma unroll
  for (int o = 32; o; o >>= 1) ls += __shfl_xor(ls, o, 64);
  if (lane == 0) red[w] = ls;
  __syncthreads();
  float tot = 0.f;
#pragma unroll
  for (int i = 0; i < 8; ++i) tot += red[i];

  float a = 0.f;
  for (int s = w; s < GCS; s += 8)
    a += sc[s] * bf2f(QK[((size_t)b * SS + s0 + s) * NN + HID + h * HDIM + lane]);
  vacc[w][lane] = a;
  __syncthreads();
  if (w == 0) {
    float v = 0.f;
#pragma unroll
    for (int i = 0; i < 8; ++i) v += vacc[i][lane];
    P[1024 + (bh * 8 + c) * 64 + lane] = v;  // unnormalized, relative to bm
    if (lane == 0) {
      P[bh * 8 + c] = bm;
      P[512 + bh * 8 + c] = tot;
    }
  }
}

// pass 2: combine chunks -> gvec + context row s=0
__global__ __launch_bounds__(64) void gattn_comb_k(const float* __restrict__ P,
                                                   float* __restrict__ ctx,
                                                   float* __restrict__ gvec) {
  const int bh = blockIdx.x, b = bh >> 4, h = bh & 15;
  const int lane = threadIdx.x;
  float pm[8];
  float m = -1e30f;
#pragma unroll
  for (int c = 0; c < 8; ++c) { pm[c] = P[bh * 8 + c]; m = fmaxf(m, pm[c]); }
  float tot = 0.f, g = 0.f;
#pragma unroll
  for (int c = 0; c < 8; ++c) {
    float e = __expf(pm[c] - m);
    tot += P[512 + bh * 8 + c] * e;
    g += P[1024 + (bh * 8 + c) * 64 + lane] * e;
  }
  g /= tot;
  gvec[b * HID + h * HDIM + lane] = g;
  ctx[(size_t)b * SS * HID + h * HDIM + lane] = g;
}

// ------------------------------------------------- local attention (4 keys/pos)
__device__ __forceinline__ void unpack16(const ushort* __restrict__ p, float* f) {
  uint4 v0 = *(const uint4*)p;
  uint4 v1 = *(const uint4*)(p + 8);
  unsigned u[8] = {v0.x, v0.y, v0.z, v0.w, v1.x, v1.y, v1.z, v1.w};
#pragma unroll
  for (int i = 0; i < 8; ++i) {
    f[2*i]   = __uint_as_float(u[i] << 16);
    f[2*i+1] = __uint_as_float(u[i] & 0xffff0000u);
  }
}

__global__ __launch_bounds__(256) void local_attn_k(const ushort* __restrict__ QK,
                                                    const float* __restrict__ gvec,
                                                    float* __restrict__ out) {
  const int blk = blockIdx.x;
  const int b = blk >> 10;
  const int s = 1 + ((blk & 1023) << 2) + (int)(threadIdx.x >> 6);
  if (s >= SS) return;
  const int lane = threadIdx.x & 63;
  const int g = lane >> 2, j = lane & 3;
  const int db = g*HDIM + j*16;

  const size_t base = ((size_t)b*SS + s) * NN;
  const ushort* qp  = QK + base + db;
  const ushort* ksp = QK + base + HID + db;
  const ushort* kpp = QK + base - NN + HID + db;
  const int sn = (s == SS-1) ? 0 : s + 1;
  const ushort* knp = QK + ((size_t)b*SS + sn)*NN + HID + db;
  const float*  gvp = gvec + b*HID + db;

  float q[16], ks[16], kp[16], kn[16], gv[16];
  unpack16(qp, q); unpack16(ksp, ks); unpack16(kpp, kp); unpack16(knp, kn);
#pragma unroll
  for (int t = 0; t < 16; t += 4) *(float4*)(gv + t) = *(const float4*)(gvp + t);

  float d0=0.f, d1=0.f, d2=0.f, d3=0.f;
#pragma unroll
  for (int t = 0; t < 16; ++t) {
    d0 += q[t]*ks[t]; d1 += q[t]*gv[t]; d2 += q[t]*kp[t]; d3 += q[t]*kn[t];
  }
  d0 += __shfl_xor(d0, 1, 64); d0 += __shfl_xor(d0, 2, 64);
  d1 += __shfl_xor(d1, 1, 64); d1 += __shfl_xor(d1, 2, 64);
  d2 += __shfl_xor(d2, 1, 64); d2 += __shfl_xor(d2, 2, 64);
  d3 += __shfl_xor(d3, 1, 64); d3 += __shfl_xor(d3, 2, 64);

  float s0 = d0*0.125f, s1 = d1*0.125f, s2 = d2*0.125f, s3 = d3*0.125f;
  float m = fmaxf(fmaxf(s0, s1), fmaxf(s2, s3));
  float e0 = __expf(s0 - m), e1 = __expf(s1 - m), e2 = __expf(s2 - m), e3 = __expf(s3 - m);
  float inv = 1.f / (e0 + e1 + e2 + e3);
  float a0 = e0*inv, a1 = e1*inv, a2 = e2*inv, a3 = e3*inv;

  float o[16];
#pragma unroll
  for (int t = 0; t < 16; ++t) o[t] = a0*ks[t] + a1*gv[t] + a2*kp[t] + a3*kn[t];
  float* cp = out + ((size_t)b*SS + s)*HID + db;
#pragma unroll
  for (int t = 0; t < 16; t += 4) *(float4*)(cp + t) = *(const float4*)(o + t);

  if (j == 0) {
    float4 av; av.x = a0; av.y = a1; av.z = a2; av.w = a3;
    *(float4*)(out + (size_t)BB*SS*HID + (((size_t)b*NHEADS + g)*(SS-1) + (s-1))*4) = av;
  }
}

// ---------------------------------------------------------------------- launch
extern "C" void kernel_launch(void* const* d_in, const int* in_sizes, int n_in,
                              void* d_out, int out_size, void* d_ws, size_t ws_size,
                              hipStream_t stream) {
  const float* hs   = (const float*)d_in[0];
  const float* mask = (const float*)d_in[1];
  const float* Wq   = (const float*)d_in[2];
  const float* bq   = (const float*)d_in[3];
  const float* Wkv  = (const float*)d_in[4];
  const float* bkv  = (const float*)d_in[5];
  float* out = (float*)d_out;

  char* ws = (char*)d_ws;
  ushort* hsb  = (ushort*)ws;                                   // 32 MB
  ushort* Bt   = (ushort*)(ws + 33554432);                      // 4 MB
  ushort* QK   = (ushort*)(ws + 33554432 + 4194304);            // 64 MB
  float*  gvec = (float*)(ws + 33554432 + 4194304 + 67108864);  // 16 KB
  float*  P    = (float*)(ws + 33554432 + 4194304 + 67108864 + 16384);  // ~140 KB

  cast_hs_k<<<MM*KK/(256*8), 256, 0, stream>>>(hs, hsb);
  wcast_k<<<dim3(KK/32, NN/32), dim3(32, 8), 0, stream>>>(Wq, Wkv, Bt);
  gemm_k<<<dim3(NN/128, MM/128), 256, 0, stream>>>(hsb, Bt, bq, bkv, QK);
  gattn_part_k<<<BB*NHEADS*GCH, 512, 0, stream>>>(QK, mask, P);
  gattn_comb_k<<<BB*NHEADS, 64, 0, stream>>>(P, out, gvec);
  local_attn_k<<<BB*1024, 256, 0, stream>>>(QK, gvec, out);
}

// Round 3
// 169.967 us; speedup vs baseline: 3.2543x; 1.0632x over previous
//
#include <hip/hip_runtime.h>
#include <hip/hip_bf16.h>

#define NHEADS 16
#define HDIM   64
#define HID    1024
#define BB     4
#define SS     4096
#define MM     (BB*SS)      // 16384 rows
#define KK     HID          // 1024
#define NN     (2*HID)      // 2048 cols (Q | K)

using short8 = __attribute__((ext_vector_type(8))) short;
using f32x4  = __attribute__((ext_vector_type(4))) float;

__device__ __forceinline__ float bf2f(ushort u) {
  return __uint_as_float(((unsigned)u) << 16);
}
__device__ __forceinline__ ushort f2bf(float f) {
  unsigned u = __float_as_uint(f);
  unsigned r = (u + 0x7fffu + ((u >> 16) & 1u)) >> 16;  // RNE
  return (ushort)r;
}

__device__ __forceinline__ void gload16(const void* g, void* l) {
  __builtin_amdgcn_global_load_lds(
      (const __attribute__((address_space(1))) void*)g,
      (__attribute__((address_space(3))) void*)l, 16, 0, 0);
}

// ---------------------------------------------------------------- cast hs->bf16
__global__ __launch_bounds__(256) void cast_hs_k(const float* __restrict__ in,
                                                 ushort* __restrict__ out) {
  size_t i = ((size_t)blockIdx.x * 256 + threadIdx.x) * 8;
  float4 a = *(const float4*)(in + i);
  float4 b = *(const float4*)(in + i + 4);
  ushort r[8];
  r[0]=f2bf(a.x); r[1]=f2bf(a.y); r[2]=f2bf(a.z); r[3]=f2bf(a.w);
  r[4]=f2bf(b.x); r[5]=f2bf(b.y); r[6]=f2bf(b.z); r[7]=f2bf(b.w);
  *(uint4*)(out + i) = *(const uint4*)r;
}

// ------------------------------------------- W (K,N) -> Bt (N,K) bf16, Wq|Wkv fused
__global__ __launch_bounds__(256) void wcast_k(const float* __restrict__ Wq,
                                               const float* __restrict__ Wkv,
                                               ushort* __restrict__ Bt) {
  __shared__ float tile[32][33];
  int k0 = blockIdx.x * 32, n0 = blockIdx.y * 32;
  int tx = threadIdx.x, ty = threadIdx.y;
  const float* src = (n0 < HID) ? Wq : Wkv;
  int nc = (n0 < HID) ? n0 : n0 - HID;
#pragma unroll
  for (int j = 0; j < 4; ++j)
    tile[ty + 8*j][tx] = src[(size_t)(k0 + ty + 8*j) * HID + nc + tx];
  __syncthreads();
#pragma unroll
  for (int j = 0; j < 4; ++j)
    Bt[(size_t)(n0 + ty + 8*j) * KK + k0 + tx] = f2bf(tile[tx][ty + 8*j]);
}

// ---------------------------------------------------------------- fused QK GEMM
// 256x256 tile, BK=64, 8 waves (2Mx4N), 512 threads, 128KB LDS double-buffer.
// 8-phase counted-vmcnt schedule (T3+T4+T5). Chunk-XOR-8 swizzle on 128B rows
// (pre-swizzled global source for global_load_lds, swizzled ds_read).
// LDS byte map: buf0.A=0  buf0.B=32768  buf1.A=65536  buf1.B=98304; half1=+16384.
__global__ __launch_bounds__(512, 2) void gemm_k(const ushort* __restrict__ A,
                                                 const ushort* __restrict__ Bt,
                                                 const float* __restrict__ bq,
                                                 const float* __restrict__ bkv,
                                                 ushort* __restrict__ C) {
  extern __shared__ char lds_c[];
  const int tid = threadIdx.x;
  const int bid = blockIdx.x;
  const int wg = (bid & 7) * 64 + (bid >> 3);   // XCD swizzle (512 % 8 == 0)
  const int tm = wg >> 3, tn = wg & 7;
  const int w = tid >> 6, lane = tid & 63;
  const int wr = w >> 2, wc = w & 3;
  const int lr = lane & 15, hi = lane >> 4;

  const ushort* Ab = A  + (size_t)tm * 256 * KK;
  const ushort* Bb = Bt + (size_t)tn * 256 * KK;

  // staging geometry: half-tile = 128 rows x 64 cols = 16KB; 2 gload16/thread.
  const int o0 = tid * 16;                    // LDS byte offset of load j=0
  const int srow = tid >> 3;                  // source row 0..63 (j=0)
  const int sc = tid & 7;                     // 16B chunk 0..7
  const size_t aoff = (size_t)srow * KK + ((sc ^ (srow & 7)) << 3);  // elems

  const int swz0 = (hi ^ (lr & 7)) << 4;          // kstep 0 chunk swizzle
  const int swz1 = ((4 + hi) ^ (lr & 7)) << 4;    // kstep 1
  const int rowA = (wr * 128 + lr) * 128;         // byte offset in A region
  const int rowB = (wc * 64 + lr) * 128;          // byte offset in B region

  float biasv[4];
#pragma unroll
  for (int n = 0; n < 4; ++n) {
    int col = tn * 256 + wc * 64 + n * 16 + lr;
    biasv[n] = (col < HID) ? bq[col] : bkv[col - HID];
  }

  f32x4 acc[8][4];
#pragma unroll
  for (int M = 0; M < 8; ++M)
#pragma unroll
    for (int n = 0; n < 4; ++n) acc[M][n] = (f32x4){0.f, 0.f, 0.f, 0.f};
  short8 bfrag[4];

#define STG(PANEL, TILE, DST)                                                   \
  {                                                                             \
    const ushort* g0_ = (PANEL) + (TILE) * 64 + aoff;                           \
    gload16(g0_,         lds_c + (DST) + o0);                                   \
    gload16(g0_ + 65536, lds_c + (DST) + 8192 + o0);                            \
  }

#define LOADB(BUFB, SWZ)                                                        \
  _Pragma("unroll") for (int n = 0; n < 4; ++n)                                 \
    bfrag[n] = *(const short8*)(lds_c + (BUFB) + rowB + n * 2048 + (SWZ));

#define CPH(BUFA, MH, SWZ, STAGE_CODE, TAIL_CODE)                               \
  {                                                                             \
    short8 afrag[4];                                                            \
    _Pragma("unroll") for (int m = 0; m < 4; ++m)                               \
      afrag[m] = *(const short8*)(lds_c + (BUFA) + rowA + (MH) * 8192 +         \
                                  m * 2048 + (SWZ));                            \
    STAGE_CODE;                                                                 \
    __builtin_amdgcn_s_barrier();                                               \
    asm volatile("" ::: "memory");                                              \
    __builtin_amdgcn_s_setprio(1);                                              \
    _Pragma("unroll") for (int m = 0; m < 4; ++m)                               \
      _Pragma("unroll") for (int n = 0; n < 4; ++n)                             \
        acc[(MH) * 4 + m][n] = __builtin_amdgcn_mfma_f32_16x16x32_bf16(         \
            afrag[m], bfrag[n], acc[(MH) * 4 + m][n], 0, 0, 0);                 \
    __builtin_amdgcn_s_setprio(0);                                              \
    TAIL_CODE;                                                                  \
    __builtin_amdgcn_s_barrier();                                               \
    asm volatile("" ::: "memory");                                              \
  }

  // ---- prologue: tile0 -> buf0 (all 4 half-tiles), tile1 B.h0 -> buf1
  STG(Bb,          0, 32768);   // buf0.B.h0
  STG(Bb + 131072, 0, 49152);   // buf0.B.h1
  STG(Ab,          0, 0);       // buf0.A.h0
  STG(Ab + 131072, 0, 16384);   // buf0.A.h1
  STG(Bb,          1, 98304);   // buf1.B.h0   (stays in flight)
  asm volatile("s_waitcnt vmcnt(2)" ::: "memory");
  __builtin_amdgcn_s_barrier();
  asm volatile("" ::: "memory");

  // ---- main loop: iteration it computes tiles 2it (buf0) and 2it+1 (buf1).
  // Stages: p1-p3 finish buf1 (tile 2it+1); p4-p7 refill buf0 (tile 2it+2);
  // p8 starts buf1 (tile 2it+3). vmcnt(2) at p4 retires all 4 buf1 half-tiles;
  // vmcnt(2) at p8 retires all 4 buf0 half-tiles. Ledger: outstanding
  // oscillates 4..10 loads, never drains in steady state.
#define ITER_BODY(T1, TN0, TN1, G, VM4)                                          \
  LOADB(32768, swz0);                                                            \
  CPH(0, 0, swz0, STG(Bb + 131072, (T1), 114688), {});                           \
  CPH(0, 1, swz0, STG(Ab, (T1), 65536), {});                                     \
  LOADB(32768, swz1);                                                            \
  CPH(0, 0, swz1, STG(Ab + 131072, (T1), 81920), {});                            \
  CPH(0, 1, swz1, { if (G) STG(Bb, (TN0), 32768) },                              \
      { asm volatile("s_waitcnt vmcnt(" #VM4 ")" ::: "memory");                  \
        __builtin_amdgcn_sched_barrier(0); });                                   \
  LOADB(98304, swz0);                                                            \
  CPH(65536, 0, swz0, { if (G) STG(Bb + 131072, (TN0), 49152) }, {});            \
  CPH(65536, 1, swz0, { if (G) STG(Ab, (TN0), 0) }, {});                         \
  LOADB(98304, swz1);                                                            \
  CPH(65536, 0, swz1, { if (G) STG(Ab + 131072, (TN0), 16384) }, {});            \
  CPH(65536, 1, swz1, { if (G) STG(Bb, (TN1), 98304) },                          \
      { asm volatile("s_waitcnt vmcnt(2)" ::: "memory");                         \
        __builtin_amdgcn_sched_barrier(0); });

  for (int it = 0; it < 7; ++it) {
    ITER_BODY(2 * it + 1, 2 * it + 2, 2 * it + 3, true, 2)
  }
  ITER_BODY(15, 0, 0, false, 0)   // final: no prefetch; p4 drains fully

#undef ITER_BODY
#undef CPH
#undef LOADB
#undef STG

  // ---- epilogue: stage C tile (256x256 bf16 = 128KB) in LDS, coalesced store
  // (loop ended at a raw barrier; nothing outstanding at it==7)
#pragma unroll
  for (int M = 0; M < 8; ++M) {
#pragma unroll
    for (int n = 0; n < 4; ++n) {
#pragma unroll
      for (int t = 0; t < 4; ++t) {
        int row = wr * 128 + M * 16 + hi * 4 + t;
        int col = wc * 64 + n * 16 + lr;
        *(ushort*)(lds_c + row * 512 + ((col * 2) ^ ((row & 7) << 4))) =
            f2bf(acc[M][n][t] + biasv[n]);
      }
    }
  }
  __syncthreads();
#pragma unroll
  for (int i = 0; i < 16; ++i) {
    int idx = i * 512 + tid;
    int row = idx >> 5, l = idx & 31;
    uint4 v = *(const uint4*)(lds_c + row * 512 + ((l ^ (row & 7)) << 4));
    *(uint4*)(C + (size_t)(tm * 256 + row) * NN + tn * 256 + l * 8) = v;
  }
}

// ------------------------------------------------- global attention, split-K flash
#define GCH 8
#define GCS (SS / GCH)  // 512

__global__ __launch_bounds__(512) void gattn_part_k(const ushort* __restrict__ QK,
                                                    const float* __restrict__ mask,
                                                    float* __restrict__ P) {
  const int bh = blockIdx.x >> 3, c = blockIdx.x & 7;
  const int b = bh >> 4, h = bh & 15;
  const int tid = threadIdx.x, w = tid >> 6, lane = tid & 63;
  __shared__ float sc[GCS];
  __shared__ float red[8];
  __shared__ float vacc[8][64];

  const float gq = bf2f(QK[(size_t)b * SS * NN + h * HDIM + lane]);  // Q row s=0
  const int s0 = c * GCS;
  float mx = -1e30f;
  for (int s = w; s < GCS; s += 8) {
    float kv = bf2f(QK[((size_t)b * SS + s0 + s) * NN + HID + h * HDIM + lane]);
    float p = gq * kv;
#pragma unroll
    for (int o = 32; o; o >>= 1) p += __shfl_xor(p, o, 64);
    p = p * 0.125f + mask[b * SS + s0 + s];
    if (lane == 0) sc[s] = p;
    mx = fmaxf(mx, p);
  }
  if (lane == 0) red[w] = mx;
  __syncthreads();
  float bm = -1e30f;
#pragma unroll
  for (int i = 0; i < 8; ++i) bm = fmaxf(bm, red[i]);
  __syncthreads();
  float ls = 0.f;
  for (int s = tid; s < GCS; s += 512) {
    float e = __expf(sc[s] - bm);
    sc[s] = e;
    ls += e;
  }
#pragma unroll
  for (int o = 32; o; o >>= 1) ls += __shfl_xor(ls, o, 64);
  if (lane == 0) red[w] = ls;
  __syncthreads();
  float tot = 0.f;
#pragma unroll
  for (int i = 0; i < 8; ++i) tot += red[i];

  float a = 0.f;
  for (int s = w; s < GCS; s += 8)
    a += sc[s] * bf2f(QK[((size_t)b * SS + s0 + s) * NN + HID + h * HDIM + lane]);
  vacc[w][lane] = a;
  __syncthreads();
  if (w == 0) {
    float v = 0.f;
#pragma unroll
    for (int i = 0; i < 8; ++i) v += vacc[i][lane];
    P[1024 + (bh * 8 + c) * 64 + lane] = v;
    if (lane == 0) {
      P[bh * 8 + c] = bm;
      P[512 + bh * 8 + c] = tot;
    }
  }
}

__global__ __launch_bounds__(64) void gattn_comb_k(const float* __restrict__ P,
                                                   float* __restrict__ ctx,
                                                   float* __restrict__ gvec) {
  const int bh = blockIdx.x, b = bh >> 4, h = bh & 15;
  const int lane = threadIdx.x;
  float pm[8];
  float m = -1e30f;
#pragma unroll
  for (int c = 0; c < 8; ++c) { pm[c] = P[bh * 8 + c]; m = fmaxf(m, pm[c]); }
  float tot = 0.f, g = 0.f;
#pragma unroll
  for (int c = 0; c < 8; ++c) {
    float e = __expf(pm[c] - m);
    tot += P[512 + bh * 8 + c] * e;
    g += P[1024 + (bh * 8 + c) * 64 + lane] * e;
  }
  g /= tot;
  gvec[b * HID + h * HDIM + lane] = g;
  ctx[(size_t)b * SS * HID + h * HDIM + lane] = g;
}

// ------------------------------------------------- local attention (4 keys/pos)
__device__ __forceinline__ void unpack16(const ushort* __restrict__ p, float* f) {
  uint4 v0 = *(const uint4*)p;
  uint4 v1 = *(const uint4*)(p + 8);
  unsigned u[8] = {v0.x, v0.y, v0.z, v0.w, v1.x, v1.y, v1.z, v1.w};
#pragma unroll
  for (int i = 0; i < 8; ++i) {
    f[2*i]   = __uint_as_float(u[i] << 16);
    f[2*i+1] = __uint_as_float(u[i] & 0xffff0000u);
  }
}

__global__ __launch_bounds__(256) void local_attn_k(const ushort* __restrict__ QK,
                                                    const float* __restrict__ gvec,
                                                    float* __restrict__ out) {
  const int blk = blockIdx.x;
  const int b = blk >> 10;
  const int s = 1 + ((blk & 1023) << 2) + (int)(threadIdx.x >> 6);
  if (s >= SS) return;
  const int lane = threadIdx.x & 63;
  const int g = lane >> 2, j = lane & 3;
  const int db = g*HDIM + j*16;

  const size_t base = ((size_t)b*SS + s) * NN;
  const ushort* qp  = QK + base + db;
  const ushort* ksp = QK + base + HID + db;
  const ushort* kpp = QK + base - NN + HID + db;
  const int sn = (s == SS-1) ? 0 : s + 1;
  const ushort* knp = QK + ((size_t)b*SS + sn)*NN + HID + db;
  const float*  gvp = gvec + b*HID + db;

  float q[16], ks[16], kp[16], kn[16], gv[16];
  unpack16(qp, q); unpack16(ksp, ks); unpack16(kpp, kp); unpack16(knp, kn);
#pragma unroll
  for (int t = 0; t < 16; t += 4) *(float4*)(gv + t) = *(const float4*)(gvp + t);

  float d0=0.f, d1=0.f, d2=0.f, d3=0.f;
#pragma unroll
  for (int t = 0; t < 16; ++t) {
    d0 += q[t]*ks[t]; d1 += q[t]*gv[t]; d2 += q[t]*kp[t]; d3 += q[t]*kn[t];
  }
  d0 += __shfl_xor(d0, 1, 64); d0 += __shfl_xor(d0, 2, 64);
  d1 += __shfl_xor(d1, 1, 64); d1 += __shfl_xor(d1, 2, 64);
  d2 += __shfl_xor(d2, 1, 64); d2 += __shfl_xor(d2, 2, 64);
  d3 += __shfl_xor(d3, 1, 64); d3 += __shfl_xor(d3, 2, 64);

  float s0 = d0*0.125f, s1 = d1*0.125f, s2 = d2*0.125f, s3 = d3*0.125f;
  float m = fmaxf(fmaxf(s0, s1), fmaxf(s2, s3));
  float e0 = __expf(s0 - m), e1 = __expf(s1 - m), e2 = __expf(s2 - m), e3 = __expf(s3 - m);
  float inv = 1.f / (e0 + e1 + e2 + e3);
  float a0 = e0*inv, a1 = e1*inv, a2 = e2*inv, a3 = e3*inv;

  float o[16];
#pragma unroll
  for (int t = 0; t < 16; ++t) o[t] = a0*ks[t] + a1*gv[t] + a2*kp[t] + a3*kn[t];
  float* cp = out + ((size_t)b*SS + s)*HID + db;
#pragma unroll
  for (int t = 0; t < 16; t += 4) *(float4*)(cp + t) = *(const float4*)(o + t);

  if (j == 0) {
    float4 av; av.x = a0; av.y = a1; av.z = a2; av.w = a3;
    *(float4*)(out + (size_t)BB*SS*HID + (((size_t)b*NHEADS + g)*(SS-1) + (s-1))*4) = av;
  }
}

// ---------------------------------------------------------------------- launch
extern "C" void kernel_launch(void* const* d_in, const int* in_sizes, int n_in,
                              void* d_out, int out_size, void* d_ws, size_t ws_size,
                              hipStream_t stream) {
  const float* hs   = (const float*)d_in[0];
  const float* mask = (const float*)d_in[1];
  const float* Wq   = (const float*)d_in[2];
  const float* bq   = (const float*)d_in[3];
  const float* Wkv  = (const float*)d_in[4];
  const float* bkv  = (const float*)d_in[5];
  float* out = (float*)d_out;

  char* ws = (char*)d_ws;
  ushort* hsb  = (ushort*)ws;                                   // 32 MB
  ushort* Bt   = (ushort*)(ws + 33554432);                      // 4 MB
  ushort* QK   = (ushort*)(ws + 33554432 + 4194304);            // 64 MB
  float*  gvec = (float*)(ws + 33554432 + 4194304 + 67108864);  // 16 KB
  float*  P    = (float*)(ws + 33554432 + 4194304 + 67108864 + 16384);  // ~140 KB

  cast_hs_k<<<MM*KK/(256*8), 256, 0, stream>>>(hs, hsb);
  wcast_k<<<dim3(KK/32, NN/32), dim3(32, 8), 0, stream>>>(Wq, Wkv, Bt);
  gemm_k<<<dim3((MM/256)*(NN/256)), dim3(512), 131072, stream>>>(hsb, Bt, bq, bkv, QK);
  gattn_part_k<<<BB*NHEADS*GCH, 512, 0, stream>>>(QK, mask, P);
  gattn_comb_k<<<BB*NHEADS, 64, 0, stream>>>(P, out, gvec);
  local_attn_k<<<BB*1024, 256, 0, stream>>>(QK, gvec, out);
}